// Round 13
// baseline (3434.982 us; speedup 1.0000x reference)
//
#include <hip/hip_runtime.h>
#include <hip/hip_fp16.h>
#include <stdint.h>

typedef int i32x4 __attribute__((ext_vector_type(4)));

#define BM 512
#define BN 512
#define BKB 64            // K-bytes (= int8 elems) per tile
#define SLOT 65536        // A 32KB + B 32KB per slot; 2 slots = 128KB
#define THREADS 1024

__device__ __forceinline__ void gload_lds16(const void* g, void* l) {
  __builtin_amdgcn_global_load_lds(
      (const __attribute__((address_space(1))) unsigned int*)g,
      (__attribute__((address_space(3))) unsigned int*)l, 16, 0, 0);
}

// ---------------- quantize x: fp32(fp16 values) -> int8, grid-stride --------
__global__ __launch_bounds__(256) void quant_x_kernel(
    const float* __restrict__ x, const float* __restrict__ deltap,
    const float* __restrict__ zpp, int8_t* __restrict__ q, int n16) {
  const float rdelta = 1.0f / deltap[0];
  const float zp = zpp[0];
  for (int i = blockIdx.x * blockDim.x + threadIdx.x; i < n16;
       i += gridDim.x * blockDim.x) {
    const float4* src = (const float4*)x + (size_t)i * 4;
    int packed[4];
#pragma unroll
    for (int g = 0; g < 4; ++g) {
      float4 v = src[g];
      float f0 = fminf(127.f, fmaxf(-128.f, rintf(fmaf(v.x, rdelta, zp))));
      float f1 = fminf(127.f, fmaxf(-128.f, rintf(fmaf(v.y, rdelta, zp))));
      float f2 = fminf(127.f, fmaxf(-128.f, rintf(fmaf(v.z, rdelta, zp))));
      float f3 = fminf(127.f, fmaxf(-128.f, rintf(fmaf(v.w, rdelta, zp))));
      int q0 = (int)f0 & 255, q1 = (int)f1 & 255, q2 = (int)f2 & 255, q3 = (int)f3 & 255;
      packed[g] = q0 | (q1 << 8) | (q2 << 16) | (q3 << 24);
    }
    ((int4*)q)[i] = make_int4(packed[0], packed[1], packed[2], packed[3]);
  }
}

// ---------------- pack W: int32 -> int8, 16 elems/thread --------------------
__global__ __launch_bounds__(256) void pack_w_kernel(
    const int* __restrict__ w, int8_t* __restrict__ wp, int n16) {
  int i = blockIdx.x * blockDim.x + threadIdx.x;
  if (i >= n16) return;
  const int4* src = (const int4*)w + (size_t)i * 4;
  int packed[4];
#pragma unroll
  for (int g = 0; g < 4; ++g) {
    int4 v = src[g];
    packed[g] = (v.x & 255) | ((v.y & 255) << 8) | ((v.z & 255) << 16) | ((v.w & 255) << 24);
  }
  ((int4*)wp)[i] = make_int4(packed[0], packed[1], packed[2], packed[3]);
}

// ---------------- int8 GEMM, 512x512 tile (int8-only geometry) --------------
// Staged bytes/op halve vs 256x256 (1/BM+1/BN): 0.5 GB total vs 1 GB.
// 16 waves (4M x 4N), wave-tile 128x128, acc[8][8] i32x4 (256 VGPR, ~340
// total, cap 512 at 4 waves/SIMD). 16 ds_read_b128 -> 64 MFMA per wave/tile.
// r8 ledger unchanged: 2-slot dbuf, stage(t+1) inside tile, single
// vmcnt(0)+barrier per tile. r4-verified chunk-XOR swizzle (rows 64B).
// Grid = 64x4 = 256 blocks = exactly 1/CU; hand XCD map groups the 4
// bn-blocks of each bm on one XCD (A-panel HBM-once, L2-served 3x).
__global__ __launch_bounds__(THREADS, 4) void gemm_i8_kernel(
    const int8_t* __restrict__ Aq, const int8_t* __restrict__ Bw,
    const float* __restrict__ atwd, const float* __restrict__ zpws,
    const float* __restrict__ bias, float* __restrict__ out,
    int Mc, int Nc, int Kc) {
  __shared__ int8_t lds[2 * SLOT];

  const int nbn = Nc / BN;
  const int nbm = Mc / BM;
  int bm, bn;
  if (nbm * nbn == 256 && nbn == 4) {
    // xcd = b&7 gets 32 blocks = 8 bm-groups x 4 bn
    const int b = blockIdx.x;
    const int s = b >> 3;
    bm = (b & 7) * 8 + (s >> 2);
    bn = s & 3;
  } else {
    bm = blockIdx.x / nbn;
    bn = blockIdx.x % nbn;
  }

  const int tid = threadIdx.x;
  const size_t K = (size_t)Kc;
  const int NT = Kc / BKB;

  // ---- staging: sweep = 1024 thr x 16B = 16KB = 256 rows x 64B ----
  const int srow = tid >> 2;                        // 0..255
  const int lc = (tid & 3) ^ ((tid >> 3) & 3);      // inverse-swizzled chunk
  const int8_t* gA = Aq + ((size_t)(bm * BM + srow)) * K + lc * 16;
  const int8_t* gB = Bw + ((size_t)(bn * BN + srow)) * K + lc * 16;
  const size_t row256 = (size_t)256 * K;
  int8_t* ldst = &lds[tid * 16];

  auto stage = [&](int t, int slot) {   // 4 gloads: A 2x16KB, B 2x16KB
    int8_t* l = ldst + slot * SLOT;
    const size_t koff = (size_t)t * BKB;
    gload_lds16(gA + koff, l);
    gload_lds16(gA + koff + row256, l + 16384);
    gload_lds16(gB + koff, l + 32768);
    gload_lds16(gB + koff + row256, l + 49152);
  };

  // ---- fragment geometry: 16 waves 4x4, wave-tile 128x128 ----
  const int lane = tid & 63;
  const int wave = tid >> 6;
  const int wr = wave >> 2;          // 0..3 -> 128-row strips
  const int wc = wave & 3;           // 0..3 -> 128-col strips
  const int fr = lane & 15;
  const int kc = lane >> 4;
  const int coff = ((kc ^ ((fr >> 1) & 3)) << 4);  // swizzled ds_read chunk
  const int aRow = wr * 128 + fr;
  const int bRow = wc * 128 + fr;

  i32x4 acc[8][8] = {};

  // ---- prologue ----
  stage(0, 0);
  asm volatile("s_waitcnt vmcnt(0)" ::: "memory");
  __builtin_amdgcn_s_barrier();
  __builtin_amdgcn_sched_barrier(0);

  for (int t = 0; t < NT; ++t) {
    const int8_t* sA = &lds[(t & 1) * SLOT];
    const int8_t* sB = sA + 32768;

    i32x4 af[8], bf[8];
#pragma unroll
    for (int j = 0; j < 8; ++j)
      bf[j] = *(const i32x4*)&sB[(bRow + j * 16) * 64 + coff];
#pragma unroll
    for (int i = 0; i < 8; ++i)
      af[i] = *(const i32x4*)&sA[(aRow + i * 16) * 64 + coff];

    if (t + 1 < NT) stage(t + 1, (t + 1) & 1);

#pragma unroll
    for (int i = 0; i < 8; ++i)
#pragma unroll
      for (int j = 0; j < 8; ++j)
        acc[i][j] = __builtin_amdgcn_mfma_i32_16x16x64_i8(af[i], bf[j], acc[i][j], 0, 0, 0);

    // ---- tile boundary: U(t+1) landed, collective barrier ----
    if (t < NT - 1) {
      asm volatile("s_waitcnt vmcnt(0)" ::: "memory");
      __builtin_amdgcn_s_barrier();
      __builtin_amdgcn_sched_barrier(0);
    }
  }

  // ---- epilogue: C/D col=lane&15, row=(lane>>4)*4+reg; j innermost ----
  const int r4 = (lane >> 4) << 2;
  const int cn0 = bn * BN + wc * 128 + fr;
  float aw8[8], zs8[8], bs8[8];
#pragma unroll
  for (int j = 0; j < 8; ++j) {
    aw8[j] = atwd[cn0 + j * 16];
    zs8[j] = zpws[cn0 + j * 16];
    bs8[j] = bias[cn0 + j * 16];
  }
#pragma unroll
  for (int i = 0; i < 8; ++i) {
#pragma unroll
    for (int r = 0; r < 4; ++r) {
      const size_t rbase = (size_t)(bm * BM + wr * 128 + i * 16 + r4 + r) * (size_t)Nc;
#pragma unroll
      for (int j = 0; j < 8; ++j) {
        float v = (float)acc[i][j][r] * aw8[j] - zs8[j] + bs8[j];
        v = __half2float(__float2half(v));  // match fp16 output rounding
        out[rbase + cn0 + j * 16] = v;
      }
    }
  }
}

extern "C" void kernel_launch(void* const* d_in, const int* in_sizes, int n_in,
                              void* d_out, int out_size, void* d_ws, size_t ws_size,
                              hipStream_t stream) {
  const float* x         = (const float*)d_in[0];
  const float* act_delta = (const float*)d_in[1];
  const float* act_zp    = (const float*)d_in[2];
  const float* zpws      = (const float*)d_in[3];
  const float* atwd      = (const float*)d_in[4];
  const float* bias      = (const float*)d_in[5];
  const int*   w32       = (const int*)d_in[6];
  float* out = (float*)d_out;

  const int N = in_sizes[5];
  const int K = in_sizes[6] / N;
  const int M = in_sizes[0] / K;

  int8_t* q  = (int8_t*)d_ws;               // M*K bytes
  int8_t* wp = q + (size_t)M * K;           // N*K bytes

  {
    int n16 = (M * K) / 16;
    int grid = (n16 + 255) / 256;
    if (grid > 2048) grid = 2048;
    quant_x_kernel<<<grid, 256, 0, stream>>>(x, act_delta, act_zp, q, n16);
  }
  {
    int n16 = (N * K) / 16;
    pack_w_kernel<<<(n16 + 255) / 256, 256, 0, stream>>>(w32, wp, n16);
  }
  {
    dim3 grid((M / BM) * (N / BN));
    gemm_i8_kernel<<<grid, THREADS, 0, stream>>>(q, wp, atwd, zpws, bias, out, M, N, K);
  }
}

// Round 14
// 306.733 us; speedup vs baseline: 11.1986x; 11.1986x over previous
//
#include <hip/hip_runtime.h>
#include <hip/hip_fp16.h>
#include <stdint.h>

typedef int i32x4 __attribute__((ext_vector_type(4)));

#define BM 128
#define BN 256
#define BKB 128           // K-bytes (= int8 elems) per tile
#define NSLOT 3
#define SLOT_BYTES 49152  // A 16KB + B 32KB per slot; 3 slots = 144KB
#define THREADS 512

__device__ __forceinline__ void gload_lds16(const void* g, void* l) {
  __builtin_amdgcn_global_load_lds(
      (const __attribute__((address_space(1))) unsigned int*)g,
      (__attribute__((address_space(3))) unsigned int*)l, 16, 0, 0);
}

// ---------------- quantize x: fp32(fp16 values) -> int8, grid-stride --------
__global__ __launch_bounds__(256) void quant_x_kernel(
    const float* __restrict__ x, const float* __restrict__ deltap,
    const float* __restrict__ zpp, int8_t* __restrict__ q, int n16) {
  const float rdelta = 1.0f / deltap[0];
  const float zp = zpp[0];
  for (int i = blockIdx.x * blockDim.x + threadIdx.x; i < n16;
       i += gridDim.x * blockDim.x) {
    const float4* src = (const float4*)x + (size_t)i * 4;
    int packed[4];
#pragma unroll
    for (int g = 0; g < 4; ++g) {
      float4 v = src[g];
      float f0 = fminf(127.f, fmaxf(-128.f, rintf(fmaf(v.x, rdelta, zp))));
      float f1 = fminf(127.f, fmaxf(-128.f, rintf(fmaf(v.y, rdelta, zp))));
      float f2 = fminf(127.f, fmaxf(-128.f, rintf(fmaf(v.z, rdelta, zp))));
      float f3 = fminf(127.f, fmaxf(-128.f, rintf(fmaf(v.w, rdelta, zp))));
      int q0 = (int)f0 & 255, q1 = (int)f1 & 255, q2 = (int)f2 & 255, q3 = (int)f3 & 255;
      packed[g] = q0 | (q1 << 8) | (q2 << 16) | (q3 << 24);
    }
    ((int4*)q)[i] = make_int4(packed[0], packed[1], packed[2], packed[3]);
  }
}

// ---------------- pack W: int32 -> int8, 16 elems/thread --------------------
__global__ __launch_bounds__(256) void pack_w_kernel(
    const int* __restrict__ w, int8_t* __restrict__ wp, int n16) {
  int i = blockIdx.x * blockDim.x + threadIdx.x;
  if (i >= n16) return;
  const int4* src = (const int4*)w + (size_t)i * 4;
  int packed[4];
#pragma unroll
  for (int g = 0; g < 4; ++g) {
    int4 v = src[g];
    packed[g] = (v.x & 255) | ((v.y & 255) << 8) | ((v.z & 255) << 16) | ((v.w & 255) << 24);
  }
  ((int4*)wp)[i] = make_int4(packed[0], packed[1], packed[2], packed[3]);
}

// ---------------- int8 GEMM, 128x256, reg-dbuf + sched_barrier fences -------
// r9 byte-identical EXCEPT: (1) sched_barrier(0) after each READF pins the
// issue order [ds_reads(t+1) -> MFMA(t)] so the scheduler cannot sink the
// prefetch reads down to their consumers (r9's VGPR=120 proved it did,
// re-serializing the pipes); (2) setprio(1/0) around MFMA clusters (T5).
// Ledger (r9-verified): 3 slots {regs=t, reads=t+1, DMA=t+2}; vmcnt(6)
// drains DMA(t+1) one iter early; lgkm(0)+barrier before READF proves the
// slot being overwritten next was fully read by all waves.
__global__ __launch_bounds__(THREADS, 2) void gemm_i8_kernel(
    const int8_t* __restrict__ Aq, const int8_t* __restrict__ Bw,
    const float* __restrict__ atwd, const float* __restrict__ zpws,
    const float* __restrict__ bias, float* __restrict__ out,
    int Mc, int Nc, int Kc) {
  __shared__ int8_t lds[NSLOT * SLOT_BYTES];

  // ---- T1 bijective XCD swizzle (nwg multiple of 8 here) ----
  const int nwg = gridDim.x;
  int bid = blockIdx.x;
  if ((nwg & 7) == 0) bid = (bid & 7) * (nwg >> 3) + (bid >> 3);
  const int nbn = Nc / BN;
  const int bm = bid / nbn;
  const int bn = bid % nbn;

  const int tid = threadIdx.x;
  const size_t K = (size_t)Kc;
  const int NT = Kc / BKB;

  // ---- staging: sweep = 512 thr x 16B = 8KB = 64 rows x 128B ----
  const int srow = tid >> 3;                        // 0..63
  const int cs = tid & 7;                           // storage chunk
  const int cl = cs ^ (srow & 7);                   // inverse-swizzled source
  const int8_t* gA = Aq + ((size_t)(bm * BM + srow)) * K + cl * 16;
  const int8_t* gB = Bw + ((size_t)(bn * BN + srow)) * K + cl * 16;
  const size_t row64 = (size_t)64 * K;
  int8_t* ldst = &lds[tid * 16];

  auto stage = [&](int t, int slot) {   // 6 gloads: A 2x8KB, B 4x8KB
    int8_t* l = ldst + slot * SLOT_BYTES;
    const size_t koff = (size_t)t * BKB;
#pragma unroll
    for (int r = 0; r < 2; ++r)
      gload_lds16(gA + koff + r * row64, l + r * 8192);
#pragma unroll
    for (int r = 0; r < 4; ++r)
      gload_lds16(gB + koff + r * row64, l + 16384 + r * 8192);
  };

  // ---- fragment geometry: 8 waves 2x4, wave-tile 64x64 ----
  const int lane = tid & 63;
  const int wave = tid >> 6;
  const int wr = wave >> 2;          // 0..1 -> 64-row halves of BM=128
  const int wc = wave & 3;           // 0..3 -> 64-col strips of BN=256
  const int fr = lane & 15;
  const int kc = lane >> 4;          // 16B chunk within K-half
  const int swz = fr & 7;
  const int aRow = wr * 64 + fr;
  const int bRow = wc * 64 + fr;

  i32x4 acc[4][4] = {};
  i32x4 fa0[4][2], fb0[4][2], fa1[4][2], fb1[4][2];

#define READF(AF, BF, t)                                                      \
  {                                                                           \
    const int8_t* sA_ = &lds[((t) % NSLOT) * SLOT_BYTES];                     \
    const int8_t* sB_ = sA_ + 16384;                                          \
    _Pragma("unroll") for (int ks_ = 0; ks_ < 2; ++ks_) {                     \
      const int co_ = ((ks_ * 4 + kc) ^ swz) << 4;                            \
      _Pragma("unroll") for (int i_ = 0; i_ < 4; ++i_)                        \
        AF[i_][ks_] = *(const i32x4*)&sA_[(aRow + i_ * 16) * 128 + co_];      \
      _Pragma("unroll") for (int j_ = 0; j_ < 4; ++j_)                        \
        BF[j_][ks_] = *(const i32x4*)&sB_[(bRow + j_ * 16) * 128 + co_];      \
    }                                                                         \
    __builtin_amdgcn_sched_barrier(0); /* PIN: reads issue BEFORE MFMA */     \
  }

#define DOMFMA(AF, BF)                                                        \
  __builtin_amdgcn_s_setprio(1);                                              \
  _Pragma("unroll") for (int ks_ = 0; ks_ < 2; ++ks_)                         \
    _Pragma("unroll") for (int i_ = 0; i_ < 4; ++i_)                          \
      _Pragma("unroll") for (int j_ = 0; j_ < 4; ++j_)                        \
        acc[i_][j_] = __builtin_amdgcn_mfma_i32_16x16x64_i8(                  \
            AF[i_][ks_], BF[j_][ks_], acc[i_][j_], 0, 0, 0);                  \
  __builtin_amdgcn_s_setprio(0);                                              \
  __builtin_amdgcn_sched_barrier(0);

#define SYNCN(N)                                                              \
  asm volatile("s_waitcnt vmcnt(" #N ")" ::: "memory");                       \
  asm volatile("s_waitcnt lgkmcnt(0)" ::: "memory");                          \
  __builtin_amdgcn_s_barrier();                                               \
  __builtin_amdgcn_sched_barrier(0);

  // ---- prologue: stage tiles 0,1; drain DMA(0); read frags(0) -> set0 ----
  stage(0, 0);
  stage(1, 1);
  SYNCN(6);
  READF(fa0, fb0, 0);

  for (int t = 0; t < NT; t += 2) {
    // -- even half: compute tile t (set0), prefetch frags(t+1) -> set1 --
    if (t + 2 < NT) stage(t + 2, (t + 2) % NSLOT);
    if (t + 2 < NT) { SYNCN(6); } else { SYNCN(0); }
    if (t + 1 < NT) READF(fa1, fb1, t + 1);
    DOMFMA(fa0, fb0);

    // -- odd half: compute tile t+1 (set1), prefetch frags(t+2) -> set0 --
    if (t + 3 < NT) stage(t + 3, (t + 3) % NSLOT);
    if (t + 3 < NT)      { SYNCN(6); }
    else if (t + 2 < NT) { SYNCN(0); }
    if (t + 2 < NT) READF(fa0, fb0, t + 2);
    if (t + 1 < NT) DOMFMA(fa1, fb1);
  }
#undef READF
#undef DOMFMA
#undef SYNCN

  // ---- epilogue: C/D col=lane&15, row=(lane>>4)*4+reg; j-innermost ----
  const int r4 = (lane >> 4) << 2;
  const int cn0 = bn * BN + wc * 64 + fr;
  float aw4[4], zs4[4], bs4[4];
#pragma unroll
  for (int j = 0; j < 4; ++j) {
    aw4[j] = atwd[cn0 + j * 16];
    zs4[j] = zpws[cn0 + j * 16];
    bs4[j] = bias[cn0 + j * 16];
  }
#pragma unroll
  for (int mi = 0; mi < 4; ++mi) {
#pragma unroll
    for (int r = 0; r < 4; ++r) {
      const size_t rbase = (size_t)(bm * BM + wr * 64 + mi * 16 + r4 + r) * (size_t)Nc;
#pragma unroll
      for (int j = 0; j < 4; ++j) {
        float v = (float)acc[mi][j][r] * aw4[j] - zs4[j] + bs4[j];
        v = __half2float(__float2half(v));  // match fp16 output rounding
        out[rbase + cn0 + j * 16] = v;
      }
    }
  }
}

extern "C" void kernel_launch(void* const* d_in, const int* in_sizes, int n_in,
                              void* d_out, int out_size, void* d_ws, size_t ws_size,
                              hipStream_t stream) {
  const float* x         = (const float*)d_in[0];
  const float* act_delta = (const float*)d_in[1];
  const float* act_zp    = (const float*)d_in[2];
  const float* zpws      = (const float*)d_in[3];
  const float* atwd      = (const float*)d_in[4];
  const float* bias      = (const float*)d_in[5];
  const int*   w32       = (const int*)d_in[6];
  float* out = (float*)d_out;

  const int N = in_sizes[5];
  const int K = in_sizes[6] / N;
  const int M = in_sizes[0] / K;

  int8_t* q  = (int8_t*)d_ws;               // M*K bytes
  int8_t* wp = q + (size_t)M * K;           // N*K bytes

  {
    int n16 = (M * K) / 16;
    int grid = (n16 + 255) / 256;
    if (grid > 2048) grid = 2048;
    quant_x_kernel<<<grid, 256, 0, stream>>>(x, act_delta, act_zp, q, n16);
  }
  {
    int n16 = (N * K) / 16;
    pack_w_kernel<<<(n16 + 255) / 256, 256, 0, stream>>>(w32, wp, n16);
  }
  {
    dim3 grid((M / BM) * (N / BN));
    gemm_i8_kernel<<<grid, THREADS, 0, stream>>>(q, wp, atwd, zpws, bias, out, M, N, K);
  }
}